// Round 1
// baseline (260.026 us; speedup 1.0000x reference)
//
#include <hip/hip_runtime.h>
#include <stdint.h>

// ScaledDotProductAttention: B=32, S=2048, D=64, fp32 in/out, temp=8.
// Flash-attention forward, bf16 MFMA (16x16x32), fp32 accum.
// Block = 64 q-rows, 4 waves (16 q-rows each). KV tile = 64 keys.
// K LDS [key][d], V LDS transposed [d][key], both XOR-chunk-swizzled so
// ds_read_b128 fragment reads are <=2-way bank aliased (free).

#define BATCH 32
#define SEQ   2048
#define DIM   64
#define QBLK  64
#define KVBLK 64

typedef __attribute__((ext_vector_type(4))) float          f32x4;
typedef __attribute__((ext_vector_type(8))) __bf16         bf16x8;
typedef __attribute__((ext_vector_type(8))) unsigned short ushort8;

static __device__ __forceinline__ unsigned short f2bf(float f) {
    union { float f; unsigned int u; } x; x.f = f;
    unsigned int u = x.u;
    return (unsigned short)((u + 0x7FFFu + ((u >> 16) & 1u)) >> 16); // RNE
}

static __device__ __forceinline__ ushort8 pack8(float4 a, float4 b) {
    ushort8 w;
    w[0] = f2bf(a.x); w[1] = f2bf(a.y); w[2] = f2bf(a.z); w[3] = f2bf(a.w);
    w[4] = f2bf(b.x); w[5] = f2bf(b.y); w[6] = f2bf(b.z); w[7] = f2bf(b.w);
    return w;
}

__global__ __launch_bounds__(256, 4)
void attn_fwd_kernel(const float* __restrict__ q,
                     const float* __restrict__ k,
                     const float* __restrict__ v,
                     float* __restrict__ out)
{
    const int qtile = blockIdx.x;
    const int b     = blockIdx.y;
    const int t     = threadIdx.x;
    const int wid   = t >> 6;
    const int lane  = t & 63;
    const int col   = lane & 15;   // MFMA col / B-frag col / A-frag row
    const int g     = lane >> 4;   // 16-lane group 0..3

    __shared__ unsigned short Ksh[KVBLK * DIM];      // [key][d], d-chunk ^= key&7
    __shared__ unsigned short Vsh[DIM * KVBLK];      // [d][key], key-chunk ^= d&7
    __shared__ unsigned short Psh[4][16 * KVBLK];    // per-wave [qrow][key], key-chunk ^= qrow&7

    const size_t bbase = (size_t)b * SEQ * DIM;
    const int q0 = qtile * QBLK;

    // ---- Q fragments (A-frag: row = lane&15, k(d) = f*32 + g*8 + j), pre-scaled 1/8
    bf16x8 qf[2];
    {
        const float* qrow = q + bbase + (size_t)(q0 + wid * 16 + col) * DIM;
        #pragma unroll
        for (int f = 0; f < 2; ++f) {
            const float4* p4 = (const float4*)(qrow + f * 32 + g * 8);
            float4 lo = p4[0], hi = p4[1];
            lo.x *= 0.125f; lo.y *= 0.125f; lo.z *= 0.125f; lo.w *= 0.125f;
            hi.x *= 0.125f; hi.y *= 0.125f; hi.z *= 0.125f; hi.w *= 0.125f;
            ushort8 w = pack8(lo, hi);
            qf[f] = __builtin_bit_cast(bf16x8, w);
        }
    }

    f32x4 oacc[4];
    #pragma unroll
    for (int dt = 0; dt < 4; ++dt) oacc[dt] = (f32x4){0.f, 0.f, 0.f, 0.f};
    float m[4]    = {-1e30f, -1e30f, -1e30f, -1e30f};
    float lsum[4] = {0.f, 0.f, 0.f, 0.f};

    const int skey = lane;            // staging: this thread's key row
    const int d0   = wid * 16;        // staging: this thread's d-range

    for (int kv0 = 0; kv0 < SEQ; kv0 += KVBLK) {
        __syncthreads();  // previous tile's LDS reads done

        // ---- stage K tile: [key][d] bf16, chunk-swizzled
        {
            const float* kp = k + bbase + (size_t)(kv0 + skey) * DIM + d0;
            float4 a0 = *(const float4*)(kp + 0);
            float4 a1 = *(const float4*)(kp + 4);
            float4 a2 = *(const float4*)(kp + 8);
            float4 a3 = *(const float4*)(kp + 12);
            int cb = d0 >> 3;
            int s0 = (cb + 0) ^ (skey & 7);
            int s1 = (cb + 1) ^ (skey & 7);
            *(ushort8*)&Ksh[skey * DIM + s0 * 8] = pack8(a0, a1);
            *(ushort8*)&Ksh[skey * DIM + s1 * 8] = pack8(a2, a3);
        }
        // ---- stage V tile transposed: [d][key] bf16, key-chunk swizzled
        {
            const float* vp = v + bbase + (size_t)(kv0 + skey) * DIM + d0;
            float4 b0 = *(const float4*)(vp + 0);
            float4 b1 = *(const float4*)(vp + 4);
            float4 b2 = *(const float4*)(vp + 8);
            float4 b3 = *(const float4*)(vp + 12);
            float vv[16] = { b0.x, b0.y, b0.z, b0.w, b1.x, b1.y, b1.z, b1.w,
                             b2.x, b2.y, b2.z, b2.w, b3.x, b3.y, b3.z, b3.w };
            #pragma unroll
            for (int j = 0; j < 16; ++j) {
                int d = d0 + j;
                Vsh[d * KVBLK + (((skey >> 3) ^ (d & 7)) * 8) + (skey & 7)] = f2bf(vv[j]);
            }
        }
        __syncthreads();

        // ---- S = Q K^T (per wave: 16 q-rows x 64 keys)
        f32x4 sacc[4];
        #pragma unroll
        for (int c = 0; c < 4; ++c) {
            int kk = c * 16 + col;
            bf16x8 kf0 = *(const bf16x8*)&Ksh[kk * DIM + ((0 + g) ^ (kk & 7)) * 8];
            bf16x8 kf1 = *(const bf16x8*)&Ksh[kk * DIM + ((4 + g) ^ (kk & 7)) * 8];
            f32x4 z = (f32x4){0.f, 0.f, 0.f, 0.f};
            z = __builtin_amdgcn_mfma_f32_16x16x32_bf16(qf[0], kf0, z, 0, 0, 0);
            z = __builtin_amdgcn_mfma_f32_16x16x32_bf16(qf[1], kf1, z, 0, 0, 0);
            sacc[c] = z;
        }

        // ---- online softmax (rows r: q-row = g*4+r; cols spread over 16-lane group)
        #pragma unroll
        for (int r = 0; r < 4; ++r) {
            float tm = fmaxf(fmaxf(sacc[0][r], sacc[1][r]),
                             fmaxf(sacc[2][r], sacc[3][r]));
            #pragma unroll
            for (int off = 1; off < 16; off <<= 1)
                tm = fmaxf(tm, __shfl_xor(tm, off, 64));
            float mn    = fmaxf(m[r], tm);
            float alpha = __expf(m[r] - mn);
            m[r] = mn;
            float rs = 0.f;
            int qrow = g * 4 + r;
            #pragma unroll
            for (int c = 0; c < 4; ++c) {
                float p = __expf(sacc[c][r] - mn);
                rs += p;
                int kk = c * 16 + col;
                Psh[wid][qrow * KVBLK + (((kk >> 3) ^ (qrow & 7)) * 8) + (kk & 7)] = f2bf(p);
            }
            #pragma unroll
            for (int off = 1; off < 16; off <<= 1)
                rs += __shfl_xor(rs, off, 64);
            lsum[r] = lsum[r] * alpha + rs;
            oacc[0][r] *= alpha; oacc[1][r] *= alpha;
            oacc[2][r] *= alpha; oacc[3][r] *= alpha;
        }

        // ---- O += P V  (P A-frag from per-wave LDS; same-wave DS is in-order)
        bf16x8 pf0 = *(const bf16x8*)&Psh[wid][col * KVBLK + ((0 + g) ^ (col & 7)) * 8];
        bf16x8 pf1 = *(const bf16x8*)&Psh[wid][col * KVBLK + ((4 + g) ^ (col & 7)) * 8];
        #pragma unroll
        for (int dt = 0; dt < 4; ++dt) {
            int d = dt * 16 + col;
            bf16x8 vf0 = *(const bf16x8*)&Vsh[d * KVBLK + ((0 + g) ^ (d & 7)) * 8];
            bf16x8 vf1 = *(const bf16x8*)&Vsh[d * KVBLK + ((4 + g) ^ (d & 7)) * 8];
            oacc[dt] = __builtin_amdgcn_mfma_f32_16x16x32_bf16(pf0, vf0, oacc[dt], 0, 0, 0);
            oacc[dt] = __builtin_amdgcn_mfma_f32_16x16x32_bf16(pf1, vf1, oacc[dt], 0, 0, 0);
        }
    }

    // ---- epilogue: normalize and store fp32
    #pragma unroll
    for (int r = 0; r < 4; ++r) {
        float inv = 1.0f / lsum[r];
        size_t row = bbase + (size_t)(q0 + wid * 16 + g * 4 + r) * DIM;
        #pragma unroll
        for (int dt = 0; dt < 4; ++dt)
            out[row + dt * 16 + col] = oacc[dt][r] * inv;
    }
}

extern "C" void kernel_launch(void* const* d_in, const int* in_sizes, int n_in,
                              void* d_out, int out_size, void* d_ws, size_t ws_size,
                              hipStream_t stream) {
    const float* q = (const float*)d_in[0];
    const float* k = (const float*)d_in[1];
    const float* v = (const float*)d_in[2];
    float* out = (float*)d_out;
    dim3 grid(SEQ / QBLK, BATCH);
    dim3 block(256);
    hipLaunchKernelGGL(attn_fwd_kernel, grid, block, 0, stream, q, k, v, out);
}

// Round 2
// 137.519 us; speedup vs baseline: 1.8908x; 1.8908x over previous
//
#include <hip/hip_runtime.h>
#include <stdint.h>

// ScaledDotProductAttention: B=32, S=2048, D=64, fp32 in/out, temp=8.
// Swapped-operand flash attention, 32x32x16 bf16 MFMA, fp32 accum.
// S^T = mfma(K,Q)  -> lane owns one q-row -> in-register softmax.
// O^T = mfma(V^T,P^T) -> scalar alpha rescale; P^T built via cvt_pk+permlane32_swap.
// V consumed from linear [key][d] LDS via ds_read_b64_tr_b16 (HW transpose).

#define BATCH 32
#define SEQ   2048
#define DIM   64
#define QBLK_WAVE 32
#define NWAVES 4
#define QBLK  (QBLK_WAVE*NWAVES)   // 128 q-rows per block
#define KVBLK 64
#define NT    (SEQ/KVBLK)          // 32 tiles

typedef __attribute__((ext_vector_type(8)))  __bf16   bf16x8;
typedef __attribute__((ext_vector_type(16))) float    f32x16;
typedef __attribute__((ext_vector_type(2)))  unsigned uint2v;
typedef __attribute__((ext_vector_type(4)))  unsigned uint4v;

static __device__ __forceinline__ unsigned cvt_pk(float lo, float hi) {
    unsigned r; asm("v_cvt_pk_bf16_f32 %0, %1, %2" : "=v"(r) : "v"(lo), "v"(hi)); return r;
}
static __device__ __forceinline__ float exp2v(float x) {
    float r; asm("v_exp_f32 %0, %1" : "=v"(r) : "v"(x)); return r;
}
// value held by lane^32 (both halves active)
static __device__ __forceinline__ float other_half(float v, int hi) {
    unsigned u = __builtin_bit_cast(unsigned, v);
    uint2v r = __builtin_amdgcn_permlane32_swap(u, u, false, false);
    return __builtin_bit_cast(float, hi ? r[0] : r[1]);
}

#define MFMA32(A, B, C) __builtin_amdgcn_mfma_f32_32x32x16_bf16((A), (B), (C), 0, 0, 0)
#define TRR(dst, OFFSTR) \
    asm volatile("ds_read_b64_tr_b16 %0, %1 offset:" OFFSTR : "=v"(dst) : "v"(trbase))

static __device__ __forceinline__ bf16x8 frag_of(uint2v r0, uint2v r1) {
    uint4v w = { r0[0], r0[1], r1[0], r1[1] };
    return __builtin_bit_cast(bf16x8, w);
}

__global__ __launch_bounds__(256, 2)
void attn_fwd_kernel(const float* __restrict__ q,
                     const float* __restrict__ k,
                     const float* __restrict__ v,
                     float* __restrict__ out)
{
    __shared__ unsigned short Ksh[KVBLK * DIM];  // [key][d] bf16, 16B-chunk ^= (key&7)
    __shared__ unsigned short Vsh[KVBLK * DIM];  // same layout

    // T1: chunked XCD swizzle — each XCD gets 4 contiguous batches (512 blocks, 512%8==0)
    const int id    = blockIdx.x;
    const int swz   = (id & 7) * ((SEQ / QBLK) * BATCH / 8) + (id >> 3);
    const int batch = swz >> 4;            // 16 qtiles per batch
    const int qtile = swz & 15;

    const int t    = threadIdx.x;
    const int lane = t & 63;
    const int wid  = t >> 6;
    const int hi   = lane >> 5;
    const int l31  = lane & 31;
    const int l7   = lane & 7;

    const size_t bbase = (size_t)batch * SEQ * DIM;
    const int q0w = qtile * QBLK + wid * QBLK_WAVE;

    // ---- Q B-frags (B[k=d][n=q]: n=lane&31, k=hi*8+j per 16-d block), scale 1/8*log2e
    bf16x8 qf[4];
    {
        const float sc = 0.125f * 1.44269504088896341f;
        const float* qp = q + bbase + (size_t)(q0w + l31) * DIM + hi * 8;
        #pragma unroll
        for (int dblk = 0; dblk < 4; ++dblk) {
            float4 f0 = *(const float4*)(qp + dblk * 16);
            float4 f1 = *(const float4*)(qp + dblk * 16 + 4);
            uint4v w = { cvt_pk(f0.x * sc, f0.y * sc), cvt_pk(f0.z * sc, f0.w * sc),
                         cvt_pk(f1.x * sc, f1.y * sc), cvt_pk(f1.z * sc, f1.w * sc) };
            qf[dblk] = __builtin_bit_cast(bf16x8, w);
        }
    }

    // ---- staging assignment: thread t covers key-row t>>2, d-range (t&3)*16 (coalesced)
    const int srow = t >> 2, sq = t & 3;
    const float* kg = k + bbase + (size_t)srow * DIM + sq * 16;
    const float* vg = v + bbase + (size_t)srow * DIM + sq * 16;
    const int ch0 = ((2 * sq)     ^ (srow & 7)) * 8;   // swizzled chunk offsets (shorts)
    const int ch1 = ((2 * sq + 1) ^ (srow & 7)) * 8;
    unsigned short* ksta = &Ksh[srow * DIM];
    unsigned short* vsta = &Vsh[srow * DIM];

    // ---- tr_read per-lane base: in-lane fetches V[key_p][d_p..d_p+3] (swizzled)
    const int bq = (l31 & 15) >> 2, ee = (lane >> 4) & 1, cc = lane & 3;
    const unsigned vb = (unsigned)(uintptr_t)Vsh;
    const unsigned trbase = vb + (unsigned)((8 * hi + bq) * 128 +
                                            (((2 * ee + (cc >> 1)) ^ bq) * 16) + (cc & 1) * 8);

    // ---- K A-frag row base (row = kb*32 + l31; row&7 == l7 for both kb)
    const unsigned short* krow = &Ksh[l31 * DIM];

    f32x16 oacc0, oacc1;
    #pragma unroll
    for (int r = 0; r < 16; ++r) { oacc0[r] = 0.f; oacc1[r] = 0.f; }
    float m_run = -3.0e38f, l_run = 0.0f;

    // ---- prologue: load tile 0 into regs
    float4 rk[4], rv[4];
    #pragma unroll
    for (int i = 0; i < 4; ++i) {
        rk[i] = *(const float4*)(kg + i * 4);
        rv[i] = *(const float4*)(vg + i * 4);
    }

    #pragma unroll 1
    for (int tile = 0; tile < NT; ++tile) {
        __syncthreads();   // previous tile's LDS reads complete

        // ---- write staged regs -> LDS (cvt_pk packing, 4x ds_write_b128)
        {
            uint4v kw0 = { cvt_pk(rk[0].x, rk[0].y), cvt_pk(rk[0].z, rk[0].w),
                           cvt_pk(rk[1].x, rk[1].y), cvt_pk(rk[1].z, rk[1].w) };
            uint4v kw1 = { cvt_pk(rk[2].x, rk[2].y), cvt_pk(rk[2].z, rk[2].w),
                           cvt_pk(rk[3].x, rk[3].y), cvt_pk(rk[3].z, rk[3].w) };
            uint4v vw0 = { cvt_pk(rv[0].x, rv[0].y), cvt_pk(rv[0].z, rv[0].w),
                           cvt_pk(rv[1].x, rv[1].y), cvt_pk(rv[1].z, rv[1].w) };
            uint4v vw1 = { cvt_pk(rv[2].x, rv[2].y), cvt_pk(rv[2].z, rv[2].w),
                           cvt_pk(rv[3].x, rv[3].y), cvt_pk(rv[3].z, rv[3].w) };
            *(uint4v*)&ksta[ch0] = kw0;
            *(uint4v*)&ksta[ch1] = kw1;
            *(uint4v*)&vsta[ch0] = vw0;
            *(uint4v*)&vsta[ch1] = vw1;
        }
        // ---- T14: issue next tile's global loads (latency hides under compute)
        if (tile + 1 < NT) {
            const float* kg2 = kg + (size_t)(tile + 1) * KVBLK * DIM;
            const float* vg2 = vg + (size_t)(tile + 1) * KVBLK * DIM;
            #pragma unroll
            for (int i = 0; i < 4; ++i) {
                rk[i] = *(const float4*)(kg2 + i * 4);
                rv[i] = *(const float4*)(vg2 + i * 4);
            }
        }
        __syncthreads();   // tile staged

        // ---- S^T = K Q^T : sacc[kb] over keys kb*32+crow(r,hi), col q=l31
        f32x16 s0, s1;
        #pragma unroll
        for (int r = 0; r < 16; ++r) { s0[r] = 0.f; s1[r] = 0.f; }
        #pragma unroll
        for (int dblk = 0; dblk < 4; ++dblk) {
            int cofs = (((2 * dblk + hi) ^ l7) * 8);
            bf16x8 kf0 = *(const bf16x8*)&krow[cofs];
            bf16x8 kf1 = *(const bf16x8*)&krow[32 * DIM + cofs];
            s0 = MFMA32(kf0, qf[dblk], s0);
            s1 = MFMA32(kf1, qf[dblk], s1);
        }

        // ---- issue V^T tr_reads now (latency hides under softmax)
        uint2v m0k0r0, m0k0r1, m0k1r0, m0k1r1, m0k2r0, m0k2r1, m0k3r0, m0k3r1;
        uint2v m1k0r0, m1k0r1, m1k1r0, m1k1r1, m1k2r0, m1k2r1, m1k3r0, m1k3r1;
        TRR(m0k0r0, "0");    TRR(m0k0r1, "576");
        TRR(m0k1r0, "2048"); TRR(m0k1r1, "2624");
        TRR(m0k2r0, "4096"); TRR(m0k2r1, "4672");
        TRR(m0k3r0, "6144"); TRR(m0k3r1, "6720");
        TRR(m1k0r0, "64");   TRR(m1k0r1, "512");
        TRR(m1k1r0, "2112"); TRR(m1k1r1, "2560");
        TRR(m1k2r0, "4160"); TRR(m1k2r1, "4608");
        TRR(m1k3r0, "6208"); TRR(m1k3r1, "6656");

        // ---- online softmax, fully in-register (lane owns q = l31)
        float tm = s0[0];
        #pragma unroll
        for (int r = 1; r < 16; ++r) tm = fmaxf(tm, s0[r]);
        #pragma unroll
        for (int r = 0; r < 16; ++r) tm = fmaxf(tm, s1[r]);
        tm = fmaxf(tm, other_half(tm, hi));
        float mn    = fmaxf(m_run, tm);
        float alpha = exp2v(m_run - mn);
        m_run = mn;
        float rs = 0.f;
        #pragma unroll
        for (int r = 0; r < 16; ++r) { s0[r] = exp2v(s0[r] - mn); rs += s0[r]; }
        #pragma unroll
        for (int r = 0; r < 16; ++r) { s1[r] = exp2v(s1[r] - mn); rs += s1[r]; }
        rs += other_half(rs, hi);
        l_run = l_run * alpha + rs;
        #pragma unroll
        for (int r = 0; r < 16; ++r) { oacc0[r] *= alpha; oacc1[r] *= alpha; }

        // ---- P^T B-frags via cvt_pk + permlane32_swap (T12)
        bf16x8 bfr0, bfr1, bfr2, bfr3;
        {
            uint2v x1 = __builtin_amdgcn_permlane32_swap(cvt_pk(s0[0], s0[1]),  cvt_pk(s0[4], s0[5]),  false, false);
            uint2v x2 = __builtin_amdgcn_permlane32_swap(cvt_pk(s0[2], s0[3]),  cvt_pk(s0[6], s0[7]),  false, false);
            uint4v w = { x1[0], x2[0], x1[1], x2[1] };
            bfr0 = __builtin_bit_cast(bf16x8, w);
            uint2v y1 = __builtin_amdgcn_permlane32_swap(cvt_pk(s0[8], s0[9]),  cvt_pk(s0[12], s0[13]), false, false);
            uint2v y2 = __builtin_amdgcn_permlane32_swap(cvt_pk(s0[10], s0[11]), cvt_pk(s0[14], s0[15]), false, false);
            uint4v w2 = { y1[0], y2[0], y1[1], y2[1] };
            bfr1 = __builtin_bit_cast(bf16x8, w2);
            uint2v z1 = __builtin_amdgcn_permlane32_swap(cvt_pk(s1[0], s1[1]),  cvt_pk(s1[4], s1[5]),  false, false);
            uint2v z2 = __builtin_amdgcn_permlane32_swap(cvt_pk(s1[2], s1[3]),  cvt_pk(s1[6], s1[7]),  false, false);
            uint4v w3 = { z1[0], z2[0], z1[1], z2[1] };
            bfr2 = __builtin_bit_cast(bf16x8, w3);
            uint2v u1 = __builtin_amdgcn_permlane32_swap(cvt_pk(s1[8], s1[9]),  cvt_pk(s1[12], s1[13]), false, false);
            uint2v u2 = __builtin_amdgcn_permlane32_swap(cvt_pk(s1[10], s1[11]), cvt_pk(s1[14], s1[15]), false, false);
            uint4v w4 = { u1[0], u2[0], u1[1], u2[1] };
            bfr3 = __builtin_bit_cast(bf16x8, w4);
        }

        // ---- rule #18: drain tr_reads, fence scheduler, then PV MFMAs
        asm volatile("s_waitcnt lgkmcnt(0)" ::: "memory");
        __builtin_amdgcn_sched_barrier(0);

        oacc0 = MFMA32(frag_of(m0k0r0, m0k0r1), bfr0, oacc0);
        oacc1 = MFMA32(frag_of(m1k0r0, m1k0r1), bfr0, oacc1);
        oacc0 = MFMA32(frag_of(m0k1r0, m0k1r1), bfr1, oacc0);
        oacc1 = MFMA32(frag_of(m1k1r0, m1k1r1), bfr1, oacc1);
        oacc0 = MFMA32(frag_of(m0k2r0, m0k2r1), bfr2, oacc0);
        oacc1 = MFMA32(frag_of(m1k2r0, m1k2r1), bfr2, oacc1);
        oacc0 = MFMA32(frag_of(m0k3r0, m0k3r1), bfr3, oacc0);
        oacc1 = MFMA32(frag_of(m1k3r0, m1k3r1), bfr3, oacc1);
    }

    // ---- epilogue: O^T regs (d = mblk*32 + crow(r,hi), q = l31), normalize, store fp32
    float invl = 1.0f / l_run;
    float* op = out + bbase + (size_t)(q0w + l31) * DIM + 4 * hi;
    #pragma unroll
    for (int rq = 0; rq < 4; ++rq) {
        float4 o0 = { oacc0[4 * rq] * invl, oacc0[4 * rq + 1] * invl,
                      oacc0[4 * rq + 2] * invl, oacc0[4 * rq + 3] * invl };
        float4 o1 = { oacc1[4 * rq] * invl, oacc1[4 * rq + 1] * invl,
                      oacc1[4 * rq + 2] * invl, oacc1[4 * rq + 3] * invl };
        *(float4*)(op + 8 * rq)      = o0;
        *(float4*)(op + 32 + 8 * rq) = o1;
    }
}

extern "C" void kernel_launch(void* const* d_in, const int* in_sizes, int n_in,
                              void* d_out, int out_size, void* d_ws, size_t ws_size,
                              hipStream_t stream) {
    const float* q = (const float*)d_in[0];
    const float* k = (const float*)d_in[1];
    const float* v = (const float*)d_in[2];
    float* out = (float*)d_out;
    dim3 grid((SEQ / QBLK) * BATCH);   // 512
    dim3 block(256);
    hipLaunchKernelGGL(attn_fwd_kernel, grid, block, 0, stream, q, k, v, out);
}

// Round 3
// 133.154 us; speedup vs baseline: 1.9528x; 1.0328x over previous
//
#include <hip/hip_runtime.h>
#include <stdint.h>

// ScaledDotProductAttention: B=32, S=2048, D=64, fp32 in/out, temp=8.
// Swapped-operand flash attention, 32x32x16 bf16 MFMA, fp32 accum.
// S^T = mfma(K,Q) -> lane owns one q-row -> in-register softmax (tree-reduced,
// defer-max). O^T = mfma(V^T,P^T); P^T via cvt_pk+permlane32_swap.
// Double-buffered LDS, ONE raw s_barrier per tile (no vmcnt drain -> prefetch
// loads stay in flight across barriers).

#define BATCH 32
#define SEQ   2048
#define DIM   64
#define QBLK_WAVE 32
#define NWAVES 4
#define QBLK  (QBLK_WAVE*NWAVES)   // 128 q-rows per block
#define KVBLK 64
#define NT    (SEQ/KVBLK)          // 32 tiles
#define BUFSHORTS (KVBLK*DIM)      // 4096 shorts = 8192 B per tensor per buffer

typedef __attribute__((ext_vector_type(8)))  __bf16   bf16x8;
typedef __attribute__((ext_vector_type(16))) float    f32x16;
typedef __attribute__((ext_vector_type(2)))  unsigned uint2v;
typedef __attribute__((ext_vector_type(4)))  unsigned uint4v;

static __device__ __forceinline__ unsigned cvt_pk(float lo, float hi) {
    unsigned r; asm("v_cvt_pk_bf16_f32 %0, %1, %2" : "=v"(r) : "v"(lo), "v"(hi)); return r;
}
static __device__ __forceinline__ float exp2v(float x) {
    float r; asm("v_exp_f32 %0, %1" : "=v"(r) : "v"(x)); return r;
}
// value held by lane^32 (both halves active)
static __device__ __forceinline__ float other_half(float v, int hi) {
    unsigned u = __builtin_bit_cast(unsigned, v);
    uint2v r = __builtin_amdgcn_permlane32_swap(u, u, false, false);
    return __builtin_bit_cast(float, hi ? r[0] : r[1]);
}

#define MFMA32(A, B, C) __builtin_amdgcn_mfma_f32_32x32x16_bf16((A), (B), (C), 0, 0, 0)
#define TRR(dst, OFFSTR) \
    asm volatile("ds_read_b64_tr_b16 %0, %1 offset:" OFFSTR : "=v"(dst) : "v"(trb))
#define MAX4(a,b,c,d) fmaxf(fmaxf((a),(b)), fmaxf((c),(d)))
#define SUM4(a,b,c,d) (((a)+(b)) + ((c)+(d)))

static __device__ __forceinline__ bf16x8 frag_of(uint2v r0, uint2v r1) {
    uint4v w = { r0[0], r0[1], r1[0], r1[1] };
    return __builtin_bit_cast(bf16x8, w);
}

__global__ __launch_bounds__(256, 2)
void attn_fwd_kernel(const float* __restrict__ q,
                     const float* __restrict__ k,
                     const float* __restrict__ v,
                     float* __restrict__ out)
{
    __shared__ unsigned short Ksh[2][BUFSHORTS];  // [key][d] bf16, 16B-chunk ^= (key&7)
    __shared__ unsigned short Vsh[2][BUFSHORTS];  // same layout

    // T1: chunked XCD swizzle — 512 blocks, 64 per XCD, contiguous batches per XCD
    const int id    = blockIdx.x;
    const int swz   = (id & 7) * ((SEQ / QBLK) * BATCH / 8) + (id >> 3);
    const int batch = swz >> 4;            // 16 qtiles per batch
    const int qtile = swz & 15;

    const int t    = threadIdx.x;
    const int lane = t & 63;
    const int wid  = t >> 6;
    const int hi   = lane >> 5;
    const int l31  = lane & 31;
    const int l7   = lane & 7;

    const size_t bbase = (size_t)batch * SEQ * DIM;
    const int q0w = qtile * QBLK + wid * QBLK_WAVE;

    // ---- Q B-frags (B[k=d][n=q]: n=lane&31, k=hi*8+j per 16-d block), scale 1/8*log2e
    bf16x8 qf[4];
    {
        const float sc = 0.125f * 1.44269504088896341f;
        const float* qp = q + bbase + (size_t)(q0w + l31) * DIM + hi * 8;
        #pragma unroll
        for (int dblk = 0; dblk < 4; ++dblk) {
            float4 f0 = *(const float4*)(qp + dblk * 16);
            float4 f1 = *(const float4*)(qp + dblk * 16 + 4);
            uint4v w = { cvt_pk(f0.x * sc, f0.y * sc), cvt_pk(f0.z * sc, f0.w * sc),
                         cvt_pk(f1.x * sc, f1.y * sc), cvt_pk(f1.z * sc, f1.w * sc) };
            qf[dblk] = __builtin_bit_cast(bf16x8, w);
        }
    }

    // ---- staging: thread t covers key-row t>>2, d-range (t&3)*16 (coalesced)
    const int srow = t >> 2, sq = t & 3;
    const float* kg = k + bbase + (size_t)srow * DIM + sq * 16;
    const float* vg = v + bbase + (size_t)srow * DIM + sq * 16;
    const int ch0 = ((2 * sq)     ^ (srow & 7)) * 8;   // swizzled 16B-chunk offsets
    const int ch1 = ((2 * sq + 1) ^ (srow & 7)) * 8;

    // ---- tr_read per-lane base (buffer 0)
    const int bq = (l31 & 15) >> 2, ee = (lane >> 4) & 1, cc = lane & 3;
    const unsigned vb = (unsigned)(uintptr_t)&Vsh[0][0];
    const unsigned trbase = vb + (unsigned)((8 * hi + bq) * 128 +
                                            (((2 * ee + (cc >> 1)) ^ bq) * 16) + (cc & 1) * 8);

    f32x16 oacc0, oacc1;
    #pragma unroll
    for (int r = 0; r < 16; ++r) { oacc0[r] = 0.f; oacc1[r] = 0.f; }
    float m_run = 0.0f, l_run = 0.0f;   // defer-max: start at 0, rarely updated

    // ---- prologue: stage tile 0 into buf0, issue tile-1 loads
    float4 rk[4], rv[4];
    #pragma unroll
    for (int i = 0; i < 4; ++i) {
        rk[i] = *(const float4*)(kg + i * 4);
        rv[i] = *(const float4*)(vg + i * 4);
    }
    {
        uint4v kw0 = { cvt_pk(rk[0].x, rk[0].y), cvt_pk(rk[0].z, rk[0].w),
                       cvt_pk(rk[1].x, rk[1].y), cvt_pk(rk[1].z, rk[1].w) };
        uint4v kw1 = { cvt_pk(rk[2].x, rk[2].y), cvt_pk(rk[2].z, rk[2].w),
                       cvt_pk(rk[3].x, rk[3].y), cvt_pk(rk[3].z, rk[3].w) };
        uint4v vw0 = { cvt_pk(rv[0].x, rv[0].y), cvt_pk(rv[0].z, rv[0].w),
                       cvt_pk(rv[1].x, rv[1].y), cvt_pk(rv[1].z, rv[1].w) };
        uint4v vw1 = { cvt_pk(rv[2].x, rv[2].y), cvt_pk(rv[2].z, rv[2].w),
                       cvt_pk(rv[3].x, rv[3].y), cvt_pk(rv[3].z, rv[3].w) };
        *(uint4v*)&Ksh[0][srow * DIM + ch0] = kw0;
        *(uint4v*)&Ksh[0][srow * DIM + ch1] = kw1;
        *(uint4v*)&Vsh[0][srow * DIM + ch0] = vw0;
        *(uint4v*)&Vsh[0][srow * DIM + ch1] = vw1;
    }
    #pragma unroll
    for (int i = 0; i < 4; ++i) {
        rk[i] = *(const float4*)(kg + KVBLK * DIM + i * 4);
        rv[i] = *(const float4*)(vg + KVBLK * DIM + i * 4);
    }
    asm volatile("s_waitcnt lgkmcnt(0)" ::: "memory");

    #pragma unroll 2
    for (int tile = 0; tile < NT; ++tile) {
        const int cur = tile & 1;
        __builtin_amdgcn_s_barrier();          // raw: no vmcnt drain
        __builtin_amdgcn_sched_barrier(0);

        const unsigned short* krow = &Ksh[cur][l31 * DIM];
        const unsigned trb = trbase + (unsigned)(cur * (2 * BUFSHORTS));

        // ---- S^T = K Q^T
        f32x16 s0, s1;
        #pragma unroll
        for (int r = 0; r < 16; ++r) { s0[r] = 0.f; s1[r] = 0.f; }
        __builtin_amdgcn_s_setprio(1);
        #pragma unroll
        for (int dblk = 0; dblk < 4; ++dblk) {
            int cofs = (((2 * dblk + hi) ^ l7) * 8);
            bf16x8 kf0 = *(const bf16x8*)&krow[cofs];
            bf16x8 kf1 = *(const bf16x8*)&krow[32 * DIM + cofs];
            s0 = MFMA32(kf0, qf[dblk], s0);
            s1 = MFMA32(kf1, qf[dblk], s1);
        }
        __builtin_amdgcn_s_setprio(0);

        // ---- issue V^T tr_reads (latency hides under softmax)
        uint2v m0k0r0, m0k0r1, m0k1r0, m0k1r1, m0k2r0, m0k2r1, m0k3r0, m0k3r1;
        uint2v m1k0r0, m1k0r1, m1k1r0, m1k1r1, m1k2r0, m1k2r1, m1k3r0, m1k3r1;
        TRR(m0k0r0, "0");    TRR(m0k0r1, "576");
        TRR(m0k1r0, "2048"); TRR(m0k1r1, "2624");
        TRR(m0k2r0, "4096"); TRR(m0k2r1, "4672");
        TRR(m0k3r0, "6144"); TRR(m0k3r1, "6720");
        TRR(m1k0r0, "64");   TRR(m1k0r1, "512");
        TRR(m1k1r0, "2112"); TRR(m1k1r1, "2560");
        TRR(m1k2r0, "4160"); TRR(m1k2r1, "4608");
        TRR(m1k3r0, "6208"); TRR(m1k3r1, "6656");

        // ---- softmax: tree max, defer-max check, exp, tree sum
        {
            float a0 = MAX4(s0[0], s0[1], s0[2],  s0[3]);
            float a1 = MAX4(s0[4], s0[5], s0[6],  s0[7]);
            float a2 = MAX4(s0[8], s0[9], s0[10], s0[11]);
            float a3 = MAX4(s0[12], s0[13], s0[14], s0[15]);
            float b0 = MAX4(s1[0], s1[1], s1[2],  s1[3]);
            float b1 = MAX4(s1[4], s1[5], s1[6],  s1[7]);
            float b2 = MAX4(s1[8], s1[9], s1[10], s1[11]);
            float b3 = MAX4(s1[12], s1[13], s1[14], s1[15]);
            float pmax = MAX4(MAX4(a0, a1, a2, a3), b0, b1, b2);
            pmax = fmaxf(pmax, b3);
            pmax = fmaxf(pmax, other_half(pmax, hi));
            if (!__all(pmax - m_run <= 12.0f)) {    // T13: almost never taken
                float mn    = fmaxf(m_run, pmax);
                float alpha = exp2v(m_run - mn);
                m_run = mn;
                l_run *= alpha;
                #pragma unroll
                for (int r = 0; r < 16; ++r) { oacc0[r] *= alpha; oacc1[r] *= alpha; }
            }
        }
        #pragma unroll
        for (int r = 0; r < 16; ++r) s0[r] = exp2v(s0[r] - m_run);
        #pragma unroll
        for (int r = 0; r < 16; ++r) s1[r] = exp2v(s1[r] - m_run);
        {
            float a0 = SUM4(s0[0], s0[1], s0[2],  s0[3]);
            float a1 = SUM4(s0[4], s0[5], s0[6],  s0[7]);
            float a2 = SUM4(s0[8], s0[9], s0[10], s0[11]);
            float a3 = SUM4(s0[12], s0[13], s0[14], s0[15]);
            float b0 = SUM4(s1[0], s1[1], s1[2],  s1[3]);
            float b1 = SUM4(s1[4], s1[5], s1[6],  s1[7]);
            float b2 = SUM4(s1[8], s1[9], s1[10], s1[11]);
            float b3 = SUM4(s1[12], s1[13], s1[14], s1[15]);
            float rs = SUM4(SUM4(a0, a1, a2, a3), b0, b1, b2) + b3;
            rs += other_half(rs, hi);
            l_run += rs;
        }

        // ---- P^T B-frags via cvt_pk + permlane32_swap (T12)
        bf16x8 bfr0, bfr1, bfr2, bfr3;
        {
            uint2v x1 = __builtin_amdgcn_permlane32_swap(cvt_pk(s0[0], s0[1]),  cvt_pk(s0[4], s0[5]),  false, false);
            uint2v x2 = __builtin_amdgcn_permlane32_swap(cvt_pk(s0[2], s0[3]),  cvt_pk(s0[6], s0[7]),  false, false);
            uint4v w1 = { x1[0], x2[0], x1[1], x2[1] };
            bfr0 = __builtin_bit_cast(bf16x8, w1);
            uint2v y1 = __builtin_amdgcn_permlane32_swap(cvt_pk(s0[8], s0[9]),  cvt_pk(s0[12], s0[13]), false, false);
            uint2v y2 = __builtin_amdgcn_permlane32_swap(cvt_pk(s0[10], s0[11]), cvt_pk(s0[14], s0[15]), false, false);
            uint4v w2 = { y1[0], y2[0], y1[1], y2[1] };
            bfr1 = __builtin_bit_cast(bf16x8, w2);
            uint2v z1 = __builtin_amdgcn_permlane32_swap(cvt_pk(s1[0], s1[1]),  cvt_pk(s1[4], s1[5]),  false, false);
            uint2v z2 = __builtin_amdgcn_permlane32_swap(cvt_pk(s1[2], s1[3]),  cvt_pk(s1[6], s1[7]),  false, false);
            uint4v w3 = { z1[0], z2[0], z1[1], z2[1] };
            bfr2 = __builtin_bit_cast(bf16x8, w3);
            uint2v u1 = __builtin_amdgcn_permlane32_swap(cvt_pk(s1[8], s1[9]),  cvt_pk(s1[12], s1[13]), false, false);
            uint2v u2 = __builtin_amdgcn_permlane32_swap(cvt_pk(s1[10], s1[11]), cvt_pk(s1[14], s1[15]), false, false);
            uint4v w4 = { u1[0], u2[0], u1[1], u2[1] };
            bfr3 = __builtin_bit_cast(bf16x8, w4);
        }

        // ---- stage next tile into other buffer; issue tile+2 loads
        if (tile + 1 < NT) {
            unsigned short* kst = &Ksh[cur ^ 1][srow * DIM];
            unsigned short* vst = &Vsh[cur ^ 1][srow * DIM];
            uint4v kw0 = { cvt_pk(rk[0].x, rk[0].y), cvt_pk(rk[0].z, rk[0].w),
                           cvt_pk(rk[1].x, rk[1].y), cvt_pk(rk[1].z, rk[1].w) };
            uint4v kw1 = { cvt_pk(rk[2].x, rk[2].y), cvt_pk(rk[2].z, rk[2].w),
                           cvt_pk(rk[3].x, rk[3].y), cvt_pk(rk[3].z, rk[3].w) };
            uint4v vw0 = { cvt_pk(rv[0].x, rv[0].y), cvt_pk(rv[0].z, rv[0].w),
                           cvt_pk(rv[1].x, rv[1].y), cvt_pk(rv[1].z, rv[1].w) };
            uint4v vw1 = { cvt_pk(rv[2].x, rv[2].y), cvt_pk(rv[2].z, rv[2].w),
                           cvt_pk(rv[3].x, rv[3].y), cvt_pk(rv[3].z, rv[3].w) };
            *(uint4v*)&kst[ch0] = kw0;
            *(uint4v*)&kst[ch1] = kw1;
            *(uint4v*)&vst[ch0] = vw0;
            *(uint4v*)&vst[ch1] = vw1;
        }
        if (tile + 2 < NT) {
            const float* kp = kg + (size_t)(tile + 2) * KVBLK * DIM;
            const float* vp = vg + (size_t)(tile + 2) * KVBLK * DIM;
            #pragma unroll
            for (int i = 0; i < 4; ++i) {
                rk[i] = *(const float4*)(kp + i * 4);
                rv[i] = *(const float4*)(vp + i * 4);
            }
        }

        // ---- rule #18: drain DS (tr_reads + stage writes), fence, then PV MFMAs
        asm volatile("s_waitcnt lgkmcnt(0)" ::: "memory");
        __builtin_amdgcn_sched_barrier(0);

        __builtin_amdgcn_s_setprio(1);
        oacc0 = MFMA32(frag_of(m0k0r0, m0k0r1), bfr0, oacc0);
        oacc1 = MFMA32(frag_of(m1k0r0, m1k0r1), bfr0, oacc1);
        oacc0 = MFMA32(frag_of(m0k1r0, m0k1r1), bfr1, oacc0);
        oacc1 = MFMA32(frag_of(m1k1r0, m1k1r1), bfr1, oacc1);
        oacc0 = MFMA32(frag_of(m0k2r0, m0k2r1), bfr2, oacc0);
        oacc1 = MFMA32(frag_of(m1k2r0, m1k2r1), bfr2, oacc1);
        oacc0 = MFMA32(frag_of(m0k3r0, m0k3r1), bfr3, oacc0);
        oacc1 = MFMA32(frag_of(m1k3r0, m1k3r1), bfr3, oacc1);
        __builtin_amdgcn_s_setprio(0);
    }

    // ---- epilogue: O^T regs (d = mblk*32 + crow(r,hi), q = l31), normalize, store
    float invl = 1.0f / l_run;
    float* op = out + bbase + (size_t)(q0w + l31) * DIM + 4 * hi;
    #pragma unroll
    for (int rq = 0; rq < 4; ++rq) {
        float4 o0 = { oacc0[4 * rq] * invl, oacc0[4 * rq + 1] * invl,
                      oacc0[4 * rq + 2] * invl, oacc0[4 * rq + 3] * invl };
        float4 o1 = { oacc1[4 * rq] * invl, oacc1[4 * rq + 1] * invl,
                      oacc1[4 * rq + 2] * invl, oacc1[4 * rq + 3] * invl };
        *(float4*)(op + 8 * rq)      = o0;
        *(float4*)(op + 32 + 8 * rq) = o1;
    }
}

extern "C" void kernel_launch(void* const* d_in, const int* in_sizes, int n_in,
                              void* d_out, int out_size, void* d_ws, size_t ws_size,
                              hipStream_t stream) {
    const float* q = (const float*)d_in[0];
    const float* k = (const float*)d_in[1];
    const float* v = (const float*)d_in[2];
    float* out = (float*)d_out;
    dim3 grid((SEQ / QBLK) * BATCH);   // 512
    dim3 block(256);
    hipLaunchKernelGGL(attn_fwd_kernel, grid, block, 0, stream, q, k, v, out);
}